// Round 6
// baseline (1190.634 us; speedup 1.0000x reference)
//
#include <hip/hip_runtime.h>

#define NN 50000
#define NE 400000
#define NBATCH 8
#define DD 128

typedef unsigned short u16;
typedef __attribute__((ext_vector_type(8))) short bf16x8;
typedef __attribute__((ext_vector_type(8))) unsigned short u16x8;
typedef __attribute__((ext_vector_type(4))) unsigned short u16x4;
typedef __attribute__((ext_vector_type(4))) float f32x4;

__device__ __forceinline__ u16 f2bf(float f) {
  union { float f; unsigned u; } a; a.f = f;
  unsigned r = a.u + 0x7fffu + ((a.u >> 16) & 1u);
  return (u16)(r >> 16);
}

__device__ __forceinline__ void glds16(const void* g, void* l) {
  __builtin_amdgcn_global_load_lds(
      (const __attribute__((address_space(1))) unsigned*)g,
      (__attribute__((address_space(3))) unsigned*)l, 16, 0, 0);
}

// Convert+transpose fp32 weight [K][128] -> bf16 chunked [K/128][128 n][128 k]
__global__ void wconv_kernel(const float* __restrict__ src, u16* __restrict__ dst, int K) {
  int idx = blockIdx.x * 256 + threadIdx.x;
  if (idx >= K * 128) return;
  int k = idx >> 7, n = idx & 127;
  dst[((k >> 7) << 14) + (n << 7) + (k & 127)] = f2bf(src[idx]);
}

// fp32 -> bf16 flat copy
__global__ void xconv_kernel(const float* __restrict__ x, u16* __restrict__ xbf, int total4) {
  int i = blockIdx.x * 256 + threadIdx.x;
  if (i >= total4) return;
  f32x4 v = ((const f32x4*)x)[i];
  u16x4 o; o[0]=f2bf(v[0]); o[1]=f2bf(v[1]); o[2]=f2bf(v[2]); o[3]=f2bf(v[3]);
  ((u16x4*)xbf)[i] = o;
}

// ---------------- Edge MLP: 64-edge tile, ALL-upfront staging (R5, frozen) ----------------
__global__ __launch_bounds__(256, 2) void edge_kernel(
    const u16* __restrict__ xbf, const u16* __restrict__ eabf /*may be null*/,
    const float* __restrict__ ea_f32, const u16* __restrict__ ubf,
    const int* __restrict__ edge_index, const int* __restrict__ batch,
    const u16* __restrict__ w1, const u16* __restrict__ w2, const u16* __restrict__ w3,
    const float* __restrict__ b1, const float* __restrict__ b2, const float* __restrict__ b3,
    float* __restrict__ edge_out, float* agg,
    float* __restrict__ esum, unsigned* __restrict__ ecnt)
{
  __shared__ u16 As[4][64 * 128];       // 64 KB: all four K-chunks
  __shared__ float red[NBATCH][128];
  __shared__ int rows_s[64], cols_s[64], ebat_s[64];
  __shared__ unsigned cnt8[NBATCH];

  const int tid  = threadIdx.x;
  const int lane = tid & 63;
  const int wave = tid >> 6;
  const int wc   = wave;
  const int lr   = lane & 15;
  const int lkb  = lane >> 4;
  const int e0   = blockIdx.x * 64;

  if (tid < 64) {
    int r = edge_index[e0 + tid];
    int c = edge_index[NE + e0 + tid];
    rows_s[tid] = r; cols_s[tid] = c;
    ebat_s[tid] = batch[r];
  }
  for (int i = tid; i < NBATCH * 128; i += 256) (&red[0][0])[i] = 0.f;
  if (tid < NBATCH) cnt8[tid] = 0;

  f32x4 acc[4][2];
#pragma unroll
  for (int m = 0; m < 4; ++m)
#pragma unroll
    for (int n = 0; n < 2; ++n) { acc[m][n][0]=0.f; acc[m][n][1]=0.f; acc[m][n][2]=0.f; acc[m][n][3]=0.f; }

  __syncthreads();

#pragma unroll
  for (int c = 0; c < 4; ++c) {
    if (c == 2 && eabf == nullptr) continue;
#pragma unroll
    for (int i = 0; i < 4; ++i) {
      int rr = wave * 16 + i * 4 + (lane >> 4);
      const u16* rp;
      if (c == 0)      rp = xbf + (size_t)rows_s[rr] * DD;
      else if (c == 1) rp = xbf + (size_t)cols_s[rr] * DD;
      else if (c == 2) rp = eabf + (size_t)(e0 + rr) * DD;
      else             rp = ubf + (size_t)ebat_s[rr] * DD;
      const u16* src = rp + (((lane & 15) ^ (rr & 7)) << 3);
      u16* dst = &As[c][(wave * 16 + i * 4) * 128];
      glds16(src, dst);
    }
  }
  if (eabf == nullptr) {
#pragma unroll
    for (int j = 0; j < 4; ++j) {
      int idx = j * 64 + lane;
      int rr = wave * 16 + (idx >> 4);
      int k  = idx & 15;
      const float* p = ea_f32 + (size_t)(e0 + rr) * DD + k * 8;
      f32x4 a = *(const f32x4*)p;
      f32x4 b = *(const f32x4*)(p + 4);
      u16x8 v;
      v[0]=f2bf(a[0]); v[1]=f2bf(a[1]); v[2]=f2bf(a[2]); v[3]=f2bf(a[3]);
      v[4]=f2bf(b[0]); v[5]=f2bf(b[1]); v[6]=f2bf(b[2]); v[7]=f2bf(b[3]);
      *(u16x8*)&As[2][rr * 128 + ((k ^ (rr & 7)) << 3)] = v;
    }
  }
  __syncthreads();

  auto compute = [&](const u16* AsBuf, const u16* wsrc) {
#pragma unroll
    for (int kk = 0; kk < 4; ++kk) {
      const int k0 = kk * 32 + lkb * 8;
      bf16x8 af[4], bfv[2];
#pragma unroll
      for (int m = 0; m < 4; ++m) {
        int g = m * 16 + lr;
        int slot = kk * 4 + lkb;
        af[m] = *(const bf16x8*)(AsBuf + g * 128 + ((slot ^ (g & 7)) << 3));
      }
#pragma unroll
      for (int n = 0; n < 2; ++n)
        bfv[n] = *(const bf16x8*)(wsrc + ((wc * 32 + n * 16 + lr) << 7) + k0);
#pragma unroll
      for (int m = 0; m < 4; ++m)
#pragma unroll
        for (int n = 0; n < 2; ++n)
          acc[m][n] = __builtin_amdgcn_mfma_f32_16x16x32_bf16(af[m], bfv[n], acc[m][n], 0, 0, 0);
    }
  };

  auto epi_relu = [&](u16* HsBuf, const float* bias) {
#pragma unroll
    for (int n = 0; n < 2; ++n) {
      int colg = wc * 32 + n * 16 + lr;
      float bv = bias[colg];
      int slot = colg >> 3;
#pragma unroll
      for (int m = 0; m < 4; ++m)
#pragma unroll
        for (int r = 0; r < 4; ++r) {
          int rowg = m * 16 + lkb * 4 + r;
          float v = fmaxf(acc[m][n][r] + bv, 0.f);
          HsBuf[rowg * 128 + ((slot ^ (rowg & 7)) << 3) + (colg & 7)] = f2bf(v);
          acc[m][n][r] = 0.f;
        }
    }
  };

  compute(As[0], w1);
  compute(As[1], w1 + (1 << 14));
  compute(As[2], w1 + (2 << 14));
  compute(As[3], w1 + (3 << 14));
  __syncthreads();
  epi_relu(As[0], b1);
  __syncthreads();
  compute(As[0], w2);
  __syncthreads();
  epi_relu(As[1], b2);
  __syncthreads();
  compute(As[1], w3);

#pragma unroll
  for (int n = 0; n < 2; ++n) {
    int colg = wc * 32 + n * 16 + lr;
    float bias = b3[colg];
#pragma unroll
    for (int m = 0; m < 4; ++m)
#pragma unroll
      for (int r = 0; r < 4; ++r) {
        int rowg = m * 16 + lkb * 4 + r;
        float v = acc[m][n][r] + bias;
        edge_out[(size_t)(e0 + rowg) * DD + colg] = v;
        atomicAdd(&agg[(size_t)cols_s[rowg] * DD + colg], v);
        atomicAdd(&red[ebat_s[rowg]][colg], v);
      }
  }
  if (tid < 64) atomicAdd(&cnt8[ebat_s[tid]], 1u);
  __syncthreads();
  for (int i = tid; i < NBATCH * 128; i += 256) atomicAdd(&esum[i], (&red[0][0])[i]);
  if (tid < NBATCH) atomicAdd(&ecnt[tid], cnt8[tid]);
}

// ================= ABLATION A: gather-only (x4 reps over distinct tiles) =================
__global__ __launch_bounds__(256, 2) void ablA_kernel(
    const u16* __restrict__ xbf, const u16* __restrict__ eabf,
    const u16* __restrict__ ubf,
    const int* __restrict__ edge_index, const int* __restrict__ batch,
    float* __restrict__ sink)
{
  __shared__ u16 As[4][64 * 128];
  __shared__ int rows_s[64], cols_s[64], ebat_s[64];
  const int tid  = threadIdx.x;
  const int lane = tid & 63;
  const int wave = tid >> 6;
  int ssum = 0;
  for (int rep = 0; rep < 4; ++rep) {
    int bb = blockIdx.x + rep * 1567; if (bb >= 6250) bb -= 6250;
    int e0 = bb * 64;
    __syncthreads();
    if (tid < 64) {
      int r = edge_index[e0 + tid];
      int c = edge_index[NE + e0 + tid];
      rows_s[tid] = r; cols_s[tid] = c; ebat_s[tid] = batch[r];
    }
    __syncthreads();
#pragma unroll
    for (int c = 0; c < 4; ++c) {
#pragma unroll
      for (int i = 0; i < 4; ++i) {
        int rr = wave * 16 + i * 4 + (lane >> 4);
        const u16* rp;
        if (c == 0)      rp = xbf + (size_t)rows_s[rr] * DD;
        else if (c == 1) rp = xbf + (size_t)cols_s[rr] * DD;
        else if (c == 2) rp = eabf + (size_t)(e0 + rr) * DD;
        else             rp = ubf + (size_t)ebat_s[rr] * DD;
        const u16* src = rp + (((lane & 15) ^ (rr & 7)) << 3);
        u16* dst = &As[c][(wave * 16 + i * 4) * 128];
        glds16(src, dst);
      }
    }
    __syncthreads();   // compiler emits vmcnt(0) drain here
    // consume to keep everything live
    ssum += As[0][(tid * 67) & 8191] + As[1][(tid * 131) & 8191]
          + As[2][(tid * 29) & 8191] + As[3][(tid * 193) & 8191];
  }
  sink[blockIdx.x * 256 + tid] = (float)ssum;
}

// ================= ABLATION B: compute-only (x4 reps, uninit LDS, no gathers) =================
__global__ __launch_bounds__(256, 2) void ablB_kernel(
    const u16* __restrict__ w1, const u16* __restrict__ w2, const u16* __restrict__ w3,
    const float* __restrict__ b1, const float* __restrict__ b2,
    float* __restrict__ sink)
{
  __shared__ u16 As[4][64 * 128];
  const int tid  = threadIdx.x;
  const int lane = tid & 63;
  const int wave = tid >> 6;
  const int wc   = wave;
  const int lr   = lane & 15;
  const int lkb  = lane >> 4;

  f32x4 acc[4][2];
#pragma unroll
  for (int m = 0; m < 4; ++m)
#pragma unroll
    for (int n = 0; n < 2; ++n) { acc[m][n][0]=0.f; acc[m][n][1]=0.f; acc[m][n][2]=0.f; acc[m][n][3]=0.f; }

  auto compute = [&](const u16* AsBuf, const u16* wsrc) {
#pragma unroll
    for (int kk = 0; kk < 4; ++kk) {
      const int k0 = kk * 32 + lkb * 8;
      bf16x8 af[4], bfv[2];
#pragma unroll
      for (int m = 0; m < 4; ++m) {
        int g = m * 16 + lr;
        int slot = kk * 4 + lkb;
        af[m] = *(const bf16x8*)(AsBuf + g * 128 + ((slot ^ (g & 7)) << 3));
      }
#pragma unroll
      for (int n = 0; n < 2; ++n)
        bfv[n] = *(const bf16x8*)(wsrc + ((wc * 32 + n * 16 + lr) << 7) + k0);
#pragma unroll
      for (int m = 0; m < 4; ++m)
#pragma unroll
        for (int n = 0; n < 2; ++n)
          acc[m][n] = __builtin_amdgcn_mfma_f32_16x16x32_bf16(af[m], bfv[n], acc[m][n], 0, 0, 0);
    }
  };

  auto epi_relu = [&](u16* HsBuf, const float* bias) {
#pragma unroll
    for (int n = 0; n < 2; ++n) {
      int colg = wc * 32 + n * 16 + lr;
      float bv = bias[colg];
      int slot = colg >> 3;
#pragma unroll
      for (int m = 0; m < 4; ++m)
#pragma unroll
        for (int r = 0; r < 4; ++r) {
          int rowg = m * 16 + lkb * 4 + r;
          float v = fmaxf(acc[m][n][r] + bv, 0.f);
          HsBuf[rowg * 128 + ((slot ^ (rowg & 7)) << 3) + (colg & 7)] = f2bf(v);
          acc[m][n][r] = 0.f;
        }
    }
  };

  for (int rep = 0; rep < 4; ++rep) {
    compute(As[0], w1);
    compute(As[1], w1 + (1 << 14));
    compute(As[2], w1 + (2 << 14));
    compute(As[3], w1 + (3 << 14));
    __syncthreads();
    epi_relu(As[0], b1);
    __syncthreads();
    compute(As[0], w2);
    __syncthreads();
    epi_relu(As[1], b2);
    __syncthreads();
    compute(As[1], w3);
    __syncthreads();
  }
  float s = 0.f;
#pragma unroll
  for (int m = 0; m < 4; ++m)
#pragma unroll
    for (int n = 0; n < 2; ++n)
#pragma unroll
      for (int r = 0; r < 4; ++r) s += acc[m][n][r];
  sink[blockIdx.x * 256 + tid] = s;
}

// ---------------- Node MLP: 2-phase pipelined (R5, frozen) ----------------
__global__ __launch_bounds__(256, 2) void node_kernel(
    const u16* __restrict__ xbf, float* aggx /* agg in, x_out out */,
    const u16* __restrict__ ubf, const int* __restrict__ batch,
    const u16* __restrict__ w1, const u16* __restrict__ w2, const u16* __restrict__ w3,
    const float* __restrict__ b1, const float* __restrict__ b2, const float* __restrict__ b3,
    float* __restrict__ nsum, unsigned* __restrict__ ncnt)
{
  __shared__ u16 As[2][128 * 128];
  __shared__ float red[NBATCH][128];
  __shared__ int nbat_s[128];
  __shared__ unsigned cnt8[NBATCH];

  const int tid  = threadIdx.x;
  const int lane = tid & 63;
  const int wave = tid >> 6;
  const int wr = wave >> 1, wc = wave & 1;
  const int lr  = lane & 15;
  const int lkb = lane >> 4;
  const int n0  = blockIdx.x * 128;
  const int bcol = wc * 64 + lr;

  if (tid < 128) {
    int node = n0 + tid;
    nbat_s[tid] = (node < NN) ? batch[node] : 0;
  }
  for (int i = tid; i < NBATCH * 128; i += 256) (&red[0][0])[i] = 0.f;
  if (tid < NBATCH) cnt8[tid] = 0;

  f32x4 acc[4][4];
#pragma unroll
  for (int m = 0; m < 4; ++m)
#pragma unroll
    for (int n = 0; n < 4; ++n) { acc[m][n][0]=0.f; acc[m][n][1]=0.f; acc[m][n][2]=0.f; acc[m][n][3]=0.f; }

  __syncthreads();

  auto stage_bf = [&](int buf, int c) {
#pragma unroll
    for (int i = 0; i < 8; ++i) {
      int rr = wave * 32 + i * 4 + (lane >> 4);
      int node = n0 + rr; if (node >= NN) node = 0;
      const u16* rp = (c == 0) ? (xbf + (size_t)node * DD)
                               : (ubf + (size_t)nbat_s[rr] * DD);
      int sd = lane & 15;
      const u16* src = rp + ((sd ^ (rr & 7)) << 3);
      u16* dst = &As[buf][(wave * 32 + i * 4) * 128];
      glds16(src, dst);
    }
  };

  auto stage_agg = [&](int buf) {
#pragma unroll
    for (int j = 0; j < 8; ++j) {
      int t = j * 64 + lane;
      int rr = wave * 32 + (t >> 4);
      int k  = t & 15;
      int node = n0 + rr; if (node >= NN) node = 0;
      const float* p = aggx + (size_t)node * DD + k * 8;
      f32x4 a = *(const f32x4*)p;
      f32x4 b = *(const f32x4*)(p + 4);
      u16x8 v;
      v[0]=f2bf(a[0]); v[1]=f2bf(a[1]); v[2]=f2bf(a[2]); v[3]=f2bf(a[3]);
      v[4]=f2bf(b[0]); v[5]=f2bf(b[1]); v[6]=f2bf(b[2]); v[7]=f2bf(b[3]);
      *(u16x8*)&As[buf][rr * 128 + ((k ^ (rr & 7)) << 3)] = v;
    }
  };

  auto compute = [&](const u16* AsBuf, const u16* wsrc) {
#pragma unroll
    for (int kk = 0; kk < 4; ++kk) {
      const int k0 = kk * 32 + lkb * 8;
      bf16x8 af[4], bfv[4];
#pragma unroll
      for (int m = 0; m < 4; ++m) {
        int g = wr * 64 + m * 16 + lr;
        int slot = kk * 4 + lkb;
        af[m] = *(const bf16x8*)(AsBuf + g * 128 + ((slot ^ (g & 7)) << 3));
      }
#pragma unroll
      for (int n = 0; n < 4; ++n)
        bfv[n] = *(const bf16x8*)(wsrc + ((bcol + n * 16) << 7) + k0);
#pragma unroll
      for (int m = 0; m < 4; ++m)
#pragma unroll
        for (int n = 0; n < 4; ++n)
          acc[m][n] = __builtin_amdgcn_mfma_f32_16x16x32_bf16(af[m], bfv[n], acc[m][n], 0, 0, 0);
    }
  };

  auto epi_relu = [&](u16* HsBuf, const float* bias) {
#pragma unroll
    for (int n = 0; n < 4; ++n) {
      int colg = wc * 64 + n * 16 + lr;
      float bv = bias[colg];
      int slot = colg >> 3;
#pragma unroll
      for (int m = 0; m < 4; ++m)
#pragma unroll
        for (int r = 0; r < 4; ++r) {
          int rowg = wr * 64 + m * 16 + lkb * 4 + r;
          float v = fmaxf(acc[m][n][r] + bv, 0.f);
          HsBuf[rowg * 128 + ((slot ^ (rowg & 7)) << 3) + (colg & 7)] = f2bf(v);
          acc[m][n][r] = 0.f;
        }
    }
  };

  stage_bf(0, 0);
  __syncthreads();
  stage_agg(1); compute(As[0], w1);               __syncthreads();
  stage_bf(0, 2); compute(As[1], w1 + (1 << 14)); __syncthreads();
                  compute(As[0], w1 + (2 << 14));
  epi_relu(As[1], b1);
  __syncthreads();
  compute(As[1], w2);
  __syncthreads();
  epi_relu(As[0], b2);
  __syncthreads();
  compute(As[0], w3);

#pragma unroll
  for (int n = 0; n < 4; ++n) {
    int colg = wc * 64 + n * 16 + lr;
    float bias = b3[colg];
#pragma unroll
    for (int m = 0; m < 4; ++m)
#pragma unroll
      for (int r = 0; r < 4; ++r) {
        int rowg = wr * 64 + m * 16 + lkb * 4 + r;
        int node = n0 + rowg;
        if (node < NN) {
          float v = acc[m][n][r] + bias;
          aggx[(size_t)node * DD + colg] = v;
          atomicAdd(&red[nbat_s[rowg]][colg], v);
        }
      }
  }
  if (tid < 128 && (n0 + tid) < NN) atomicAdd(&cnt8[nbat_s[tid]], 1u);
  __syncthreads();
  for (int i = tid; i < NBATCH * 128; i += 256) atomicAdd(&nsum[i], (&red[0][0])[i]);
  if (tid < NBATCH) atomicAdd(&ncnt[tid], cnt8[tid]);
}

// ---------------- Global MLP (fp32, tiny) ----------------
__global__ void global_kernel(
    const float* __restrict__ u,
    const float* __restrict__ nsum, const unsigned* __restrict__ ncnt,
    const float* __restrict__ esum, const unsigned* __restrict__ ecnt,
    const float* __restrict__ gW1, const float* __restrict__ gb1,
    const float* __restrict__ gW2, const float* __restrict__ gb2,
    const float* __restrict__ gW3, const float* __restrict__ gb3,
    float* __restrict__ u_out)
{
  __shared__ float gin[NBATCH][384];
  __shared__ float h1[NBATCH][128];
  __shared__ float h2[NBATCH][128];
  int tid = threadIdx.x;
  for (int i = tid; i < NBATCH * 128; i += 256) {
    int r = i >> 7, c = i & 127;
    float nc = (float)(ncnt[r] < 1u ? 1u : ncnt[r]);
    float ec = (float)(ecnt[r] < 1u ? 1u : ecnt[r]);
    gin[r][c] = u[i];
    gin[r][128 + c] = nsum[i] / nc;
    gin[r][256 + c] = esum[i] / ec;
  }
  __syncthreads();
  for (int o = tid; o < NBATCH * 128; o += 256) {
    int r = o >> 7, n = o & 127;
    float s = gb1[n];
    for (int k = 0; k < 384; ++k) s += gin[r][k] * gW1[k * 128 + n];
    h1[r][n] = fmaxf(s, 0.f);
  }
  __syncthreads();
  for (int o = tid; o < NBATCH * 128; o += 256) {
    int r = o >> 7, n = o & 127;
    float s = gb2[n];
    for (int k = 0; k < 128; ++k) s += h1[r][k] * gW2[k * 128 + n];
    h2[r][n] = fmaxf(s, 0.f);
  }
  __syncthreads();
  for (int o = tid; o < NBATCH * 128; o += 256) {
    int r = o >> 7, n = o & 127;
    float s = gb3[n];
    for (int k = 0; k < 128; ++k) s += h2[r][k] * gW3[k * 128 + n];
    u_out[o] = s;
  }
}

extern "C" void kernel_launch(void* const* d_in, const int* in_sizes, int n_in,
                              void* d_out, int out_size, void* d_ws, size_t ws_size,
                              hipStream_t stream) {
  const float* x          = (const float*)d_in[0];
  const int*   edge_index = (const int*)d_in[1];
  const float* edge_attr  = (const float*)d_in[2];
  const float* u          = (const float*)d_in[3];
  const int*   batch      = (const int*)d_in[4];
  const float* eW1 = (const float*)d_in[5];  const float* eb1 = (const float*)d_in[6];
  const float* eW2 = (const float*)d_in[7];  const float* eb2 = (const float*)d_in[8];
  const float* eW3 = (const float*)d_in[9];  const float* eb3 = (const float*)d_in[10];
  const float* nW1 = (const float*)d_in[11]; const float* nb1 = (const float*)d_in[12];
  const float* nW2 = (const float*)d_in[13]; const float* nb2 = (const float*)d_in[14];
  const float* nW3 = (const float*)d_in[15]; const float* nb3 = (const float*)d_in[16];
  const float* gW1 = (const float*)d_in[17]; const float* gb1 = (const float*)d_in[18];
  const float* gW2 = (const float*)d_in[19]; const float* gb2 = (const float*)d_in[20];
  const float* gW3 = (const float*)d_in[21]; const float* gb3 = (const float*)d_in[22];

  float* out      = (float*)d_out;
  float* xout_agg = out;                                  // [NN][128]: agg then x_out
  float* edge_out = out + (size_t)NN * DD;                // [NE][128]
  float* u_out    = out + (size_t)(NN + NE) * DD;         // [8][128]

  char* ws = (char*)d_ws;
  u16* wE1t = (u16*)(ws + 0);         // 131072
  u16* wE2t = (u16*)(ws + 131072);    // 32768
  u16* wE3t = (u16*)(ws + 163840);    // 32768
  u16* wN1t = (u16*)(ws + 196608);    // 98304
  u16* wN2t = (u16*)(ws + 294912);    // 32768
  u16* wN3t = (u16*)(ws + 327680);    // 32768
  float*    esum = (float*)(ws + 360448);     // 4096
  float*    nsum = (float*)(ws + 364544);     // 4096
  unsigned* ecnt = (unsigned*)(ws + 368640);  // 32
  unsigned* ncnt = (unsigned*)(ws + 368672);  // 32
  u16*      ubf  = (u16*)(ws + 369664);       // 2048
  u16*      xbf  = (u16*)(ws + 393216);       // 12,800,000 -> ends 13,193,216
  const size_t EABF_OFF = 13193216;
  const size_t EABF_END = EABF_OFF + (size_t)NE * DD * 2; // 115,593,216
  u16* eabf = (ws_size >= EABF_END) ? (u16*)(ws + EABF_OFF) : nullptr;
  // ablation sinks live inside the eabf region (consumed before ablations run;
  // rewritten by xconv each launch)
  float* sinkA = (float*)(ws + EABF_OFF);                 // 6.4 MB
  float* sinkB = (float*)(ws + EABF_OFF + (size_t)32 * 1024 * 1024);

  hipMemsetAsync(d_out, 0, (size_t)NN * DD * sizeof(float), stream);
  hipMemsetAsync(ws + 360448, 0, 8288, stream);

  wconv_kernel<<<256, 256, 0, stream>>>(eW1, wE1t, 512);
  wconv_kernel<<<64, 256, 0, stream>>>(eW2, wE2t, 128);
  wconv_kernel<<<64, 256, 0, stream>>>(eW3, wE3t, 128);
  wconv_kernel<<<192, 256, 0, stream>>>(nW1, wN1t, 384);
  wconv_kernel<<<64, 256, 0, stream>>>(nW2, wN2t, 128);
  wconv_kernel<<<64, 256, 0, stream>>>(nW3, wN3t, 128);
  xconv_kernel<<<6250, 256, 0, stream>>>(x, xbf, NN * DD / 4);
  xconv_kernel<<<1, 256, 0, stream>>>(u, ubf, NBATCH * DD / 4);
  if (eabf)
    xconv_kernel<<<50000, 256, 0, stream>>>(edge_attr, eabf, NE * DD / 4);

  edge_kernel<<<NE / 64, 256, 0, stream>>>(
      xbf, eabf, edge_attr, ubf, edge_index, batch,
      wE1t, wE2t, wE3t, eb1, eb2, eb3,
      edge_out, xout_agg, esum, ecnt);

  node_kernel<<<(NN + 127) / 128, 256, 0, stream>>>(
      xbf, xout_agg, ubf, batch,
      wN1t, wN2t, wN3t, nb1, nb2, nb3,
      nsum, ncnt);

  global_kernel<<<1, 256, 0, stream>>>(
      u, nsum, ncnt, esum, ecnt,
      gW1, gb1, gW2, gb2, gW3, gb3, u_out);

  // ---- ablation dispatches (write only ws scratch; run after all consumers)
  if (eabf) {
    ablA_kernel<<<NE / 64, 256, 0, stream>>>(xbf, eabf, ubf, edge_index, batch, sinkA);
    ablB_kernel<<<NE / 64, 256, 0, stream>>>(wE1t, wE2t, wE3t, eb1, eb2, sinkB);
  }
}

// Round 7
// 624.424 us; speedup vs baseline: 1.9068x; 1.9068x over previous
//
#include <hip/hip_runtime.h>

#define NN 50000
#define NE 400000
#define NBATCH 8
#define DD 128

typedef unsigned short u16;
typedef __attribute__((ext_vector_type(8))) short bf16x8;
typedef __attribute__((ext_vector_type(8))) unsigned short u16x8;
typedef __attribute__((ext_vector_type(4))) unsigned short u16x4;
typedef __attribute__((ext_vector_type(4))) float f32x4;

__device__ __forceinline__ u16 f2bf(float f) {
  union { float f; unsigned u; } a; a.f = f;
  unsigned r = a.u + 0x7fffu + ((a.u >> 16) & 1u);
  return (u16)(r >> 16);
}

__device__ __forceinline__ void glds16(const void* g, void* l) {
  __builtin_amdgcn_global_load_lds(
      (const __attribute__((address_space(1))) unsigned*)g,
      (__attribute__((address_space(3))) unsigned*)l, 16, 0, 0);
}

// Convert+transpose fp32 weight [K][128] -> bf16 chunked [K/128][128 n][128 k]
__global__ void wconv_kernel(const float* __restrict__ src, u16* __restrict__ dst, int K) {
  int idx = blockIdx.x * 256 + threadIdx.x;
  if (idx >= K * 128) return;
  int k = idx >> 7, n = idx & 127;
  dst[((k >> 7) << 14) + (n << 7) + (k & 127)] = f2bf(src[idx]);
}

// fp32 -> bf16 flat copy
__global__ void xconv_kernel(const float* __restrict__ x, u16* __restrict__ xbf, int total4) {
  int i = blockIdx.x * 256 + threadIdx.x;
  if (i >= total4) return;
  f32x4 v = ((const f32x4*)x)[i];
  u16x4 o; o[0]=f2bf(v[0]); o[1]=f2bf(v[1]); o[2]=f2bf(v[2]); o[3]=f2bf(v[3]);
  ((u16x4*)xbf)[i] = o;
}

// ---------------- Edge MLP: 64-edge tile, 32KB LDS dbuf, 4 blocks/CU ----------------
__global__ __launch_bounds__(256, 4) void edge_kernel(
    const u16* __restrict__ xbf, const u16* __restrict__ eabf /*may be null*/,
    const float* __restrict__ ea_f32, const u16* __restrict__ ubf,
    const int* __restrict__ edge_index, const int* __restrict__ batch,
    const u16* __restrict__ w1, const u16* __restrict__ w2, const u16* __restrict__ w3,
    const float* __restrict__ b1, const float* __restrict__ b2, const float* __restrict__ b3,
    float* __restrict__ edge_out, float* agg,
    float* __restrict__ esum, unsigned* __restrict__ ecnt)
{
  __shared__ u16 As[2][64 * 128];       // 32 KB double buffer
  __shared__ float red[NBATCH][128];
  __shared__ int rows_s[64], cols_s[64], ebat_s[64];
  __shared__ unsigned cnt8[NBATCH];

  const int tid  = threadIdx.x;
  const int lane = tid & 63;
  const int wave = tid >> 6;
  const int wc   = wave;                // 4 waves tile N=128 as 4 x 32 cols
  const int lr   = lane & 15;
  const int lkb  = lane >> 4;
  const int e0   = blockIdx.x * 64;

  if (tid < 64) {
    int r = edge_index[e0 + tid];
    int c = edge_index[NE + e0 + tid];
    rows_s[tid] = r; cols_s[tid] = c;
    ebat_s[tid] = batch[r];
  }
  for (int i = tid; i < NBATCH * 128; i += 256) (&red[0][0])[i] = 0.f;
  if (tid < NBATCH) cnt8[tid] = 0;

  f32x4 acc[4][2];
#pragma unroll
  for (int m = 0; m < 4; ++m)
#pragma unroll
    for (int n = 0; n < 2; ++n) { acc[m][n][0]=0.f; acc[m][n][1]=0.f; acc[m][n][2]=0.f; acc[m][n][3]=0.f; }

  __syncthreads();  // indices visible

  auto stage = [&](int buf, int c) {
    if (c == 2 && eabf == nullptr) {
      // fp32 fallback for edge_attr: reg-stage + cvt + swizzled ds_write
#pragma unroll
      for (int j = 0; j < 4; ++j) {
        int idx = j * 64 + lane;
        int rr = wave * 16 + (idx >> 4);
        int k  = idx & 15;
        const float* p = ea_f32 + (size_t)(e0 + rr) * DD + k * 8;
        f32x4 a = *(const f32x4*)p;
        f32x4 b = *(const f32x4*)(p + 4);
        u16x8 v;
        v[0]=f2bf(a[0]); v[1]=f2bf(a[1]); v[2]=f2bf(a[2]); v[3]=f2bf(a[3]);
        v[4]=f2bf(b[0]); v[5]=f2bf(b[1]); v[6]=f2bf(b[2]); v[7]=f2bf(b[3]);
        *(u16x8*)&As[buf][rr * 128 + ((k ^ (rr & 7)) << 3)] = v;
      }
      return;
    }
#pragma unroll
    for (int i = 0; i < 4; ++i) {
      int rr = wave * 16 + i * 4 + (lane >> 4);
      const u16* rp;
      if (c == 0)      rp = xbf + (size_t)rows_s[rr] * DD;
      else if (c == 1) rp = xbf + (size_t)cols_s[rr] * DD;
      else if (c == 2) rp = eabf + (size_t)(e0 + rr) * DD;
      else             rp = ubf + (size_t)ebat_s[rr] * DD;
      const u16* src = rp + (((lane & 15) ^ (rr & 7)) << 3);  // inverse-swizzled source
      u16* dst = &As[buf][(wave * 16 + i * 4) * 128];         // linear wave-uniform dest
      glds16(src, dst);
    }
  };

  auto compute = [&](const u16* AsBuf, const u16* wsrc) {
#pragma unroll
    for (int kk = 0; kk < 4; ++kk) {
      const int k0 = kk * 32 + lkb * 8;
      bf16x8 af[4], bfv[2];
#pragma unroll
      for (int m = 0; m < 4; ++m) {
        int g = m * 16 + lr;
        int slot = kk * 4 + lkb;
        af[m] = *(const bf16x8*)(AsBuf + g * 128 + ((slot ^ (g & 7)) << 3));
      }
#pragma unroll
      for (int n = 0; n < 2; ++n)
        bfv[n] = *(const bf16x8*)(wsrc + ((wc * 32 + n * 16 + lr) << 7) + k0);
#pragma unroll
      for (int m = 0; m < 4; ++m)
#pragma unroll
        for (int n = 0; n < 2; ++n)
          acc[m][n] = __builtin_amdgcn_mfma_f32_16x16x32_bf16(af[m], bfv[n], acc[m][n], 0, 0, 0);
    }
  };

  auto epi_relu = [&](u16* HsBuf, const float* bias) {
#pragma unroll
    for (int n = 0; n < 2; ++n) {
      int colg = wc * 32 + n * 16 + lr;
      float bv = bias[colg];
      int slot = colg >> 3;
#pragma unroll
      for (int m = 0; m < 4; ++m)
#pragma unroll
        for (int r = 0; r < 4; ++r) {
          int rowg = m * 16 + lkb * 4 + r;
          float v = fmaxf(acc[m][n][r] + bv, 0.f);
          HsBuf[rowg * 128 + ((slot ^ (rowg & 7)) << 3) + (colg & 7)] = f2bf(v);
          acc[m][n][r] = 0.f;
        }
    }
  };

  // ---- layer 1: 4 chunks, 2-phase (stage next, compute current, barrier)
  stage(0, 0);
  __syncthreads();
  stage(1, 1); compute(As[0], w1);                __syncthreads();
  stage(0, 2); compute(As[1], w1 + (1 << 14));    __syncthreads();
  stage(1, 3); compute(As[0], w1 + (2 << 14));    __syncthreads();
               compute(As[1], w1 + (3 << 14));
  // epilogue 1 -> As[0] (free: last read of As[0] was before previous barrier)
  epi_relu(As[0], b1);
  __syncthreads();
  compute(As[0], w2);
  __syncthreads();
  epi_relu(As[1], b2);
  __syncthreads();
  compute(As[1], w3);

  // epilogue 3: edge_out + agg scatter atomics + per-graph esum partials
#pragma unroll
  for (int n = 0; n < 2; ++n) {
    int colg = wc * 32 + n * 16 + lr;
    float bias = b3[colg];
#pragma unroll
    for (int m = 0; m < 4; ++m)
#pragma unroll
      for (int r = 0; r < 4; ++r) {
        int rowg = m * 16 + lkb * 4 + r;
        float v = acc[m][n][r] + bias;
        edge_out[(size_t)(e0 + rowg) * DD + colg] = v;
        atomicAdd(&agg[(size_t)cols_s[rowg] * DD + colg], v);
        atomicAdd(&red[ebat_s[rowg]][colg], v);
      }
  }
  if (tid < 64) atomicAdd(&cnt8[ebat_s[tid]], 1u);
  __syncthreads();
  for (int i = tid; i < NBATCH * 128; i += 256) atomicAdd(&esum[i], (&red[0][0])[i]);
  if (tid < NBATCH) atomicAdd(&ecnt[tid], cnt8[tid]);
}

// ---------------- Node MLP: 64-node tile, 32KB LDS dbuf, 4 blocks/CU ----------------
__global__ __launch_bounds__(256, 4) void node_kernel(
    const u16* __restrict__ xbf, float* aggx /* agg in, x_out out */,
    const u16* __restrict__ ubf, const int* __restrict__ batch,
    const u16* __restrict__ w1, const u16* __restrict__ w2, const u16* __restrict__ w3,
    const float* __restrict__ b1, const float* __restrict__ b2, const float* __restrict__ b3,
    float* __restrict__ nsum, unsigned* __restrict__ ncnt)
{
  __shared__ u16 As[2][64 * 128];
  __shared__ float red[NBATCH][128];
  __shared__ int nbat_s[64];
  __shared__ unsigned cnt8[NBATCH];

  const int tid  = threadIdx.x;
  const int lane = tid & 63;
  const int wave = tid >> 6;
  const int wc   = wave;
  const int lr   = lane & 15;
  const int lkb  = lane >> 4;
  const int n0   = blockIdx.x * 64;

  if (tid < 64) {
    int node = n0 + tid;
    nbat_s[tid] = (node < NN) ? batch[node] : 0;
  }
  for (int i = tid; i < NBATCH * 128; i += 256) (&red[0][0])[i] = 0.f;
  if (tid < NBATCH) cnt8[tid] = 0;

  f32x4 acc[4][2];
#pragma unroll
  for (int m = 0; m < 4; ++m)
#pragma unroll
    for (int n = 0; n < 2; ++n) { acc[m][n][0]=0.f; acc[m][n][1]=0.f; acc[m][n][2]=0.f; acc[m][n][3]=0.f; }

  __syncthreads();

  auto stage_bf = [&](int buf, int c) {   // c==0: xbf rows ; c==2: ubf rows
#pragma unroll
    for (int i = 0; i < 4; ++i) {
      int rr = wave * 16 + i * 4 + (lane >> 4);
      int node = n0 + rr; if (node >= NN) node = 0;
      const u16* rp = (c == 0) ? (xbf + (size_t)node * DD)
                               : (ubf + (size_t)nbat_s[rr] * DD);
      const u16* src = rp + (((lane & 15) ^ (rr & 7)) << 3);
      u16* dst = &As[buf][(wave * 16 + i * 4) * 128];
      glds16(src, dst);
    }
  };

  auto stage_agg = [&](int buf) {
#pragma unroll
    for (int j = 0; j < 4; ++j) {
      int idx = j * 64 + lane;
      int rr = wave * 16 + (idx >> 4);
      int k  = idx & 15;
      int node = n0 + rr; if (node >= NN) node = 0;
      const float* p = aggx + (size_t)node * DD + k * 8;
      f32x4 a = *(const f32x4*)p;
      f32x4 b = *(const f32x4*)(p + 4);
      u16x8 v;
      v[0]=f2bf(a[0]); v[1]=f2bf(a[1]); v[2]=f2bf(a[2]); v[3]=f2bf(a[3]);
      v[4]=f2bf(b[0]); v[5]=f2bf(b[1]); v[6]=f2bf(b[2]); v[7]=f2bf(b[3]);
      *(u16x8*)&As[buf][rr * 128 + ((k ^ (rr & 7)) << 3)] = v;
    }
  };

  auto compute = [&](const u16* AsBuf, const u16* wsrc) {
#pragma unroll
    for (int kk = 0; kk < 4; ++kk) {
      const int k0 = kk * 32 + lkb * 8;
      bf16x8 af[4], bfv[2];
#pragma unroll
      for (int m = 0; m < 4; ++m) {
        int g = m * 16 + lr;
        int slot = kk * 4 + lkb;
        af[m] = *(const bf16x8*)(AsBuf + g * 128 + ((slot ^ (g & 7)) << 3));
      }
#pragma unroll
      for (int n = 0; n < 2; ++n)
        bfv[n] = *(const bf16x8*)(wsrc + ((wc * 32 + n * 16 + lr) << 7) + k0);
#pragma unroll
      for (int m = 0; m < 4; ++m)
#pragma unroll
        for (int n = 0; n < 2; ++n)
          acc[m][n] = __builtin_amdgcn_mfma_f32_16x16x32_bf16(af[m], bfv[n], acc[m][n], 0, 0, 0);
    }
  };

  auto epi_relu = [&](u16* HsBuf, const float* bias) {
#pragma unroll
    for (int n = 0; n < 2; ++n) {
      int colg = wc * 32 + n * 16 + lr;
      float bv = bias[colg];
      int slot = colg >> 3;
#pragma unroll
      for (int m = 0; m < 4; ++m)
#pragma unroll
        for (int r = 0; r < 4; ++r) {
          int rowg = m * 16 + lkb * 4 + r;
          float v = fmaxf(acc[m][n][r] + bv, 0.f);
          HsBuf[rowg * 128 + ((slot ^ (rowg & 7)) << 3) + (colg & 7)] = f2bf(v);
          acc[m][n][r] = 0.f;
        }
    }
  };

  // layer 1: 3 chunks (x | agg | u), 2-phase
  stage_bf(0, 0);
  __syncthreads();
  stage_agg(1);   compute(As[0], w1);               __syncthreads();
  stage_bf(0, 2); compute(As[1], w1 + (1 << 14));   __syncthreads();
                  compute(As[0], w1 + (2 << 14));
  epi_relu(As[1], b1);
  __syncthreads();
  compute(As[1], w2);
  __syncthreads();
  epi_relu(As[0], b2);
  __syncthreads();
  compute(As[0], w3);

  // epilogue 3: x_out overwrites agg rows; node-mean partials
#pragma unroll
  for (int n = 0; n < 2; ++n) {
    int colg = wc * 32 + n * 16 + lr;
    float bias = b3[colg];
#pragma unroll
    for (int m = 0; m < 4; ++m)
#pragma unroll
      for (int r = 0; r < 4; ++r) {
        int rowg = m * 16 + lkb * 4 + r;
        int node = n0 + rowg;
        if (node < NN) {
          float v = acc[m][n][r] + bias;
          aggx[(size_t)node * DD + colg] = v;
          atomicAdd(&red[nbat_s[rowg]][colg], v);
        }
      }
  }
  if (tid < 64 && (n0 + tid) < NN) atomicAdd(&cnt8[nbat_s[tid]], 1u);
  __syncthreads();
  for (int i = tid; i < NBATCH * 128; i += 256) atomicAdd(&nsum[i], (&red[0][0])[i]);
  if (tid < NBATCH) atomicAdd(&ncnt[tid], cnt8[tid]);
}

// ---------------- Global MLP (fp32, tiny) ----------------
__global__ void global_kernel(
    const float* __restrict__ u,
    const float* __restrict__ nsum, const unsigned* __restrict__ ncnt,
    const float* __restrict__ esum, const unsigned* __restrict__ ecnt,
    const float* __restrict__ gW1, const float* __restrict__ gb1,
    const float* __restrict__ gW2, const float* __restrict__ gb2,
    const float* __restrict__ gW3, const float* __restrict__ gb3,
    float* __restrict__ u_out)
{
  __shared__ float gin[NBATCH][384];
  __shared__ float h1[NBATCH][128];
  __shared__ float h2[NBATCH][128];
  int tid = threadIdx.x;
  for (int i = tid; i < NBATCH * 128; i += 256) {
    int r = i >> 7, c = i & 127;
    float nc = (float)(ncnt[r] < 1u ? 1u : ncnt[r]);
    float ec = (float)(ecnt[r] < 1u ? 1u : ecnt[r]);
    gin[r][c] = u[i];
    gin[r][128 + c] = nsum[i] / nc;
    gin[r][256 + c] = esum[i] / ec;
  }
  __syncthreads();
  for (int o = tid; o < NBATCH * 128; o += 256) {
    int r = o >> 7, n = o & 127;
    float s = gb1[n];
    for (int k = 0; k < 384; ++k) s += gin[r][k] * gW1[k * 128 + n];
    h1[r][n] = fmaxf(s, 0.f);
  }
  __syncthreads();
  for (int o = tid; o < NBATCH * 128; o += 256) {
    int r = o >> 7, n = o & 127;
    float s = gb2[n];
    for (int k = 0; k < 128; ++k) s += h1[r][k] * gW2[k * 128 + n];
    h2[r][n] = fmaxf(s, 0.f);
  }
  __syncthreads();
  for (int o = tid; o < NBATCH * 128; o += 256) {
    int r = o >> 7, n = o & 127;
    float s = gb3[n];
    for (int k = 0; k < 128; ++k) s += h2[r][k] * gW3[k * 128 + n];
    u_out[o] = s;
  }
}

extern "C" void kernel_launch(void* const* d_in, const int* in_sizes, int n_in,
                              void* d_out, int out_size, void* d_ws, size_t ws_size,
                              hipStream_t stream) {
  const float* x          = (const float*)d_in[0];
  const int*   edge_index = (const int*)d_in[1];
  const float* edge_attr  = (const float*)d_in[2];
  const float* u          = (const float*)d_in[3];
  const int*   batch      = (const int*)d_in[4];
  const float* eW1 = (const float*)d_in[5];  const float* eb1 = (const float*)d_in[6];
  const float* eW2 = (const float*)d_in[7];  const float* eb2 = (const float*)d_in[8];
  const float* eW3 = (const float*)d_in[9];  const float* eb3 = (const float*)d_in[10];
  const float* nW1 = (const float*)d_in[11]; const float* nb1 = (const float*)d_in[12];
  const float* nW2 = (const float*)d_in[13]; const float* nb2 = (const float*)d_in[14];
  const float* nW3 = (const float*)d_in[15]; const float* nb3 = (const float*)d_in[16];
  const float* gW1 = (const float*)d_in[17]; const float* gb1 = (const float*)d_in[18];
  const float* gW2 = (const float*)d_in[19]; const float* gb2 = (const float*)d_in[20];
  const float* gW3 = (const float*)d_in[21]; const float* gb3 = (const float*)d_in[22];

  float* out      = (float*)d_out;
  float* xout_agg = out;                                  // [NN][128]: agg then x_out
  float* edge_out = out + (size_t)NN * DD;                // [NE][128]
  float* u_out    = out + (size_t)(NN + NE) * DD;         // [8][128]

  char* ws = (char*)d_ws;
  u16* wE1t = (u16*)(ws + 0);         // 131072
  u16* wE2t = (u16*)(ws + 131072);    // 32768
  u16* wE3t = (u16*)(ws + 163840);    // 32768
  u16* wN1t = (u16*)(ws + 196608);    // 98304
  u16* wN2t = (u16*)(ws + 294912);    // 32768
  u16* wN3t = (u16*)(ws + 327680);    // 32768
  float*    esum = (float*)(ws + 360448);     // 4096
  float*    nsum = (float*)(ws + 364544);     // 4096
  unsigned* ecnt = (unsigned*)(ws + 368640);  // 32
  unsigned* ncnt = (unsigned*)(ws + 368672);  // 32
  u16*      ubf  = (u16*)(ws + 369664);       // 2048
  u16*      xbf  = (u16*)(ws + 393216);       // 12,800,000 -> ends 13,193,216
  const size_t EABF_OFF = 13193216;
  const size_t EABF_END = EABF_OFF + (size_t)NE * DD * 2; // 115,593,216
  u16* eabf = (ws_size >= EABF_END) ? (u16*)(ws + EABF_OFF) : nullptr;

  // zero agg region (x_out part of d_out) and stat accumulators — every launch
  hipMemsetAsync(d_out, 0, (size_t)NN * DD * sizeof(float), stream);
  hipMemsetAsync(ws + 360448, 0, 8288, stream);

  wconv_kernel<<<256, 256, 0, stream>>>(eW1, wE1t, 512);
  wconv_kernel<<<64, 256, 0, stream>>>(eW2, wE2t, 128);
  wconv_kernel<<<64, 256, 0, stream>>>(eW3, wE3t, 128);
  wconv_kernel<<<192, 256, 0, stream>>>(nW1, wN1t, 384);
  wconv_kernel<<<64, 256, 0, stream>>>(nW2, wN2t, 128);
  wconv_kernel<<<64, 256, 0, stream>>>(nW3, wN3t, 128);
  xconv_kernel<<<6250, 256, 0, stream>>>(x, xbf, NN * DD / 4);
  xconv_kernel<<<1, 256, 0, stream>>>(u, ubf, NBATCH * DD / 4);
  if (eabf)
    xconv_kernel<<<50000, 256, 0, stream>>>(edge_attr, eabf, NE * DD / 4);

  edge_kernel<<<NE / 64, 256, 0, stream>>>(
      xbf, eabf, edge_attr, ubf, edge_index, batch,
      wE1t, wE2t, wE3t, eb1, eb2, eb3,
      edge_out, xout_agg, esum, ecnt);

  node_kernel<<<(NN + 63) / 64, 256, 0, stream>>>(
      xbf, xout_agg, ubf, batch,
      wN1t, wN2t, wN3t, nb1, nb2, nb3,
      nsum, ncnt);

  global_kernel<<<1, 256, 0, stream>>>(
      u, nsum, ncnt, esum, ecnt,
      gW1, gb1, gW2, gb2, gW3, gb3, u_out);
}